// Round 1
// 165.686 us; speedup vs baseline: 1.0597x; 1.0597x over previous
//
#include <hip/hip_runtime.h>
#include <hip/hip_bf16.h>
#include <cstdint>

// Problem constants (B=16, N=4096, D_IN=D_OUT=64)
#define NB   16
#define NN   4096
#define ND   64
#define NJ   1024   // NB*ND columns of the big GEMM

typedef __attribute__((ext_vector_type(8))) short  short8;  // 8 bf16 = 4 VGPRs
typedef __attribute__((ext_vector_type(4))) float  f32x4;

__device__ __forceinline__ unsigned short f2bf(float f) {
  union { float f; unsigned int u; } v; v.f = f;
  unsigned int u = v.u;
  unsigned int r = u + 0x7FFFu + ((u >> 16) & 1u);  // round-to-nearest-even
  return (unsigned short)(r >> 16);
}
__device__ __forceinline__ float bf2f(unsigned short h) {
  union { unsigned int u; float f; } v; v.u = ((unsigned int)h) << 16; return v.f;
}

// ---------------- K1: A fp32 -> bf16, 8 elems/thread, fully vectorized ----------------
__global__ void k_convert(const float* __restrict__ A, unsigned short* __restrict__ Ab) {
  int idx = blockIdx.x * 256 + threadIdx.x;          // 2,097,152 threads exactly
  const float4* p = (const float4*)A + (size_t)idx * 2;
  float4 a = p[0], b = p[1];
  unsigned int w0 = (unsigned int)f2bf(a.x) | ((unsigned int)f2bf(a.y) << 16);
  unsigned int w1 = (unsigned int)f2bf(a.z) | ((unsigned int)f2bf(a.w) << 16);
  unsigned int w2 = (unsigned int)f2bf(b.x) | ((unsigned int)f2bf(b.y) << 16);
  unsigned int w3 = (unsigned int)f2bf(b.z) | ((unsigned int)f2bf(b.w) << 16);
  uint4 o; o.x = w0; o.y = w1; o.z = w2; o.w = w3;
  ((uint4*)Ab)[idx] = o;                             // 16B store
}

// ---------------- K2: Yt[b*64+e][m] = sum_d Z[b][m][d]*W[d][e], fp32 math -> bf16 ----
__global__ void k_zw(const float* __restrict__ Z, const float* __restrict__ W,
                     unsigned short* __restrict__ Yt) {
  int lane = threadIdx.x & 63;
  int e0 = __builtin_amdgcn_readfirstlane((threadIdx.x >> 6) << 4);  // wave-uniform -> s_load W
  int b  = blockIdx.x >> 6;          // [0,16)
  int m0 = (blockIdx.x & 63) << 6;   // [0,4096) step 64
  int m  = m0 + lane;
  const float* zr = Z + ((size_t)b * NN + m) * ND;
  float z[64];
#pragma unroll
  for (int g = 0; g < 16; ++g) *(float4*)&z[g * 4] = ((const float4*)zr)[g];
  float acc[16];
#pragma unroll
  for (int i = 0; i < 16; ++i) acc[i] = 0.f;
#pragma unroll
  for (int d = 0; d < 64; ++d) {
    float zd = z[d];
#pragma unroll
    for (int i = 0; i < 16; ++i) acc[i] += zd * W[d * 64 + e0 + i];  // uniform addr -> SMEM
  }
#pragma unroll
  for (int i = 0; i < 16; ++i)
    Yt[(size_t)(b * 64 + e0 + i) * NN + m] = f2bf(acc[i]);
}

// ---------------- K3: 256x256-tile 8-phase GEMM, split-K x4 -------------------------
// Grid 256 blocks (= 1/CU), 512 thr = 8 waves (2M x 4N), per-wave out 128x64.
// LDS 128 KiB: A[2][256][64] shorts @0, B[2][256][64] @32768. Chunk-XOR swizzle
// (verified conflict-free in prior kernel): LDS slot s holds global chunk
// (row=s>>3, kg=(s&7)^(row&7)); ds_read chunk for (ks,quad) at (ks*4+quad)^(l15&7).
// Schedule per K-tile t (4 phases): ph1 reads all B-frags + A-quad0 and issues
// A(t+1) halves (into buf p^1, whose previous content died at (t-1,ph4));
// ph2/ph3 read A-quad1/2 and issue B(t+2) halves (into buf p B region, dead after
// ph1's reads, separated by ph1's trailing barrier); ph4 reads A-quad3 and waits
// vmcnt(4): the 4 newest loads (B(t+2)) may fly, A(t+1) [issued ph1, 4 loads] and
// B(t+1) [issued at (t-1,ph2/3), even older] are guaranteed landed -> tile t+1 ready.
// vmcnt never drains to 0 in steady state (T3+T4); setprio around MFMA (T5).
__device__ __forceinline__ void gl2lds16(const unsigned short* g, unsigned short* l) {
  __builtin_amdgcn_global_load_lds(
      (const __attribute__((address_space(1))) unsigned int*)g,
      (__attribute__((address_space(3))) unsigned int*)l, 16, 0, 0);
}

#define STAGE2(GP, LP, H) \
  gl2lds16((GP) + sOff[H][0], (LP) + dBase[H][0]); \
  gl2lds16((GP) + sOff[H][1], (LP) + dBase[H][1]);

#define READ_A(I0) \
  afr[0][0] = *(const short8*)&lt[aBase + (I0) * 1024 + c0]; \
  afr[0][1] = *(const short8*)&lt[aBase + (I0) * 1024 + c1]; \
  afr[1][0] = *(const short8*)&lt[aBase + ((I0) + 1) * 1024 + c0]; \
  afr[1][1] = *(const short8*)&lt[aBase + ((I0) + 1) * 1024 + c1];

#define MFMA_Q(I0) \
  _Pragma("unroll") \
  for (int jj = 0; jj < 4; ++jj) { \
    acc[(I0)][jj]     = __builtin_amdgcn_mfma_f32_16x16x32_bf16(afr[0][0], bfr[jj][0], acc[(I0)][jj], 0, 0, 0); \
    acc[(I0)][jj]     = __builtin_amdgcn_mfma_f32_16x16x32_bf16(afr[0][1], bfr[jj][1], acc[(I0)][jj], 0, 0, 0); \
    acc[(I0) + 1][jj] = __builtin_amdgcn_mfma_f32_16x16x32_bf16(afr[1][0], bfr[jj][0], acc[(I0) + 1][jj], 0, 0, 0); \
    acc[(I0) + 1][jj] = __builtin_amdgcn_mfma_f32_16x16x32_bf16(afr[1][1], bfr[jj][1], acc[(I0) + 1][jj], 0, 0, 0); \
  }

#define PHASE_MFMA(I0) \
  __builtin_amdgcn_s_barrier(); \
  asm volatile("s_waitcnt lgkmcnt(0)" ::: "memory"); \
  __builtin_amdgcn_s_setprio(1); \
  MFMA_Q(I0) \
  __builtin_amdgcn_s_setprio(0); \
  __builtin_amdgcn_s_barrier();

__launch_bounds__(512, 2)  // 8 waves, 1 block/CU (128 KiB LDS), VGPR cap 256
__global__ void k_gemm(const unsigned short* __restrict__ Ab,
                       const unsigned short* __restrict__ Yt,
                       unsigned short* __restrict__ Pb) {
  __shared__ unsigned short lds[65536];  // 128 KiB
  const int tid = threadIdx.x;
  const int w = tid >> 6, lane = tid & 63;
  const int quad = lane >> 4, l15 = lane & 15;
  const int wr = w >> 2, wc = w & 3;

  const int m_blk = blockIdx.x & 15;         // XCD = bx%8 = m_blk&7: 4 j_blks share
  const int j_blk = (blockIdx.x >> 4) & 3;   // one A strip per XCD L2 (2 m-strips = 4 MiB)
  const int kc    = blockIdx.x >> 6;
  const int mrow0 = m_blk << 8, jcol0 = j_blk << 8, kbase = kc << 10;

  const unsigned short* Ag = Ab + (size_t)mrow0 * 4096 + kbase;
  const unsigned short* Bg = Yt + (size_t)jcol0 * 4096 + kbase;

  // Staging offsets: half h, round r -> uniform LDS slot base h*1024+r*512+w*64,
  // per-lane slot s = base+lane, global source (row=s>>3, kg=(s&7)^(row&7)).
  int sOff[2][2], dBase[2][2];
#pragma unroll
  for (int h = 0; h < 2; ++h)
#pragma unroll
    for (int r = 0; r < 2; ++r) {
      int s = h * 1024 + r * 512 + w * 64 + lane;
      int row = s >> 3;
      int kg = (s & 7) ^ (row & 7);
      sOff[h][r]  = row * 4096 + kg * 8;
      dBase[h][r] = (h * 1024 + r * 512 + w * 64) * 8;  // wave-uniform (shorts)
    }

  // ds_read chunk offsets (shorts): row&7 == l15&7 for all fragment rows.
  const int c0 = (quad ^ (l15 & 7)) * 8;
  const int c1 = ((4 + quad) ^ (l15 & 7)) * 8;
  const int aBase = (wr * 128 + l15) * 64;            // + i*1024 + c{0,1}
  const int bBase = 32768 + (wc * 64 + l15) * 64;     // + j*1024 + c{0,1} (rel. lds+p*16384)

  f32x4 acc[8][4];
#pragma unroll
  for (int i = 0; i < 8; ++i)
#pragma unroll
    for (int j = 0; j < 4; ++j) acc[i][j] = (f32x4){0.f, 0.f, 0.f, 0.f};

  // Prologue: tile0 A+B -> buf0 (8 loads), tile1 B -> buf1 (4 loads).
  // vmcnt(4): tile0 landed, tile1-B still in flight.
  STAGE2(Ag, lds, 0) STAGE2(Ag, lds, 1)
  STAGE2(Bg, lds + 32768, 0) STAGE2(Bg, lds + 32768, 1)
  STAGE2(Bg + 64, lds + 49152, 0) STAGE2(Bg + 64, lds + 49152, 1)
  asm volatile("s_waitcnt vmcnt(4)" ::: "memory");
  __builtin_amdgcn_s_barrier();

  for (int t = 0; t < 16; ++t) {
    const int p = t & 1;
    const unsigned short* lt = lds + p * 16384;
    short8 bfr[4][2], afr[2][2];

    // ---- phase 1: all B-frags + A-quad0; issue A(t+1) halves 0,1 ----
#pragma unroll
    for (int j = 0; j < 4; ++j) {
      bfr[j][0] = *(const short8*)&lt[bBase + j * 1024 + c0];
      bfr[j][1] = *(const short8*)&lt[bBase + j * 1024 + c1];
    }
    READ_A(0)
    if (t < 15) {
      const unsigned short* g = Ag + (t + 1) * 64;
      unsigned short* lb = lds + (p ^ 1) * 16384;
      STAGE2(g, lb, 0) STAGE2(g, lb, 1)
    }
    PHASE_MFMA(0)

    // ---- phase 2: A-quad1; issue B(t+2) half 0 (tile-t B region is dead) ----
    READ_A(2)
    if (t < 14) {
      const unsigned short* g = Bg + (t + 2) * 64;
      unsigned short* lb = lds + 32768 + p * 16384;
      STAGE2(g, lb, 0)
    }
    PHASE_MFMA(2)

    // ---- phase 3: A-quad2; issue B(t+2) half 1 ----
    READ_A(4)
    if (t < 14) {
      const unsigned short* g = Bg + (t + 2) * 64;
      unsigned short* lb = lds + 32768 + p * 16384;
      STAGE2(g, lb, 1)
    }
    PHASE_MFMA(4)

    // ---- phase 4: A-quad3; counted vmcnt once per K-tile ----
    READ_A(6)
    if (t < 14) { asm volatile("s_waitcnt vmcnt(4)" ::: "memory"); }
    else if (t == 14) { asm volatile("s_waitcnt vmcnt(0)" ::: "memory"); }
    PHASE_MFMA(6)
  }

  // Epilogue: C/D layout col=l15, row=quad*4+reg (verified mapping, unchanged).
  unsigned short* P = Pb + (size_t)kc * ((size_t)NN * NJ);
  const int r0base = mrow0 + wr * 128;
  const int cb = jcol0 + wc * 64;
#pragma unroll
  for (int i = 0; i < 8; ++i) {
    const int r0 = r0base + i * 16 + quad * 4;
#pragma unroll
    for (int j = 0; j < 4; ++j) {
      const int jc = cb + j * 16 + l15;
      unsigned short* pp = P + (size_t)r0 * NJ + jc;
#pragma unroll
      for (int rg = 0; rg < 4; ++rg)
        pp[(size_t)rg * NJ] = f2bf(acc[i][j][rg]);
    }
  }
}

// ---------------- K4: out[m-major] = sum_kc P[kc]; 8 floats/thread ------------------
__global__ void k_reduce(const unsigned short* __restrict__ P, float* __restrict__ out) {
  int t = blockIdx.x * 256 + threadIdx.x;      // 524,288 threads exactly
  size_t of = (size_t)t * 8;                   // out flat index (8 consecutive floats)
  int bidx = t >> 15;                          // of >> 18
  int rem  = (int)(of & 262143);               // within one batch: m*64 + e
  int m = rem >> 6, e = rem & 63;
  size_t pj = (size_t)m * NJ + bidx * 64 + e;  // P row-index: [m][j= bidx*64+e]
  float s[8];
#pragma unroll
  for (int u = 0; u < 8; ++u) s[u] = 0.f;
#pragma unroll
  for (int kc = 0; kc < 4; ++kc) {
    short8 v = *(const short8*)(P + (size_t)kc * (NN * NJ) + pj);  // 16B load
#pragma unroll
    for (int u = 0; u < 8; ++u) s[u] += bf2f((unsigned short)v[u]);
  }
  float4 o0 = {s[0], s[1], s[2], s[3]}, o1 = {s[4], s[5], s[6], s[7]};
  ((float4*)(out + of))[0] = o0;
  ((float4*)(out + of))[1] = o1;
}

extern "C" void kernel_launch(void* const* d_in, const int* in_sizes, int n_in,
                              void* d_out, int out_size, void* d_ws, size_t ws_size,
                              hipStream_t stream) {
  const float* Z = (const float*)d_in[0];   // [16][4096][64] fp32
  const float* A = (const float*)d_in[1];   // [4096][4096] fp32
  const float* W = (const float*)d_in[2];   // [64][64] fp32
  float* out = (float*)d_out;               // [16][4096][64] fp32

  unsigned short* Ab = (unsigned short*)d_ws;                                     // 32 MiB bf16 A
  unsigned short* Yt = (unsigned short*)((char*)d_ws + (size_t)32 * 1024 * 1024); // 8 MiB bf16 Y^T
  unsigned short* Pb = (unsigned short*)((char*)d_ws + (size_t)40 * 1024 * 1024); // 32 MiB bf16 partials x4

  k_convert<<<8192, 256, 0, stream>>>(A, Ab);
  k_zw<<<1024, 256, 0, stream>>>(Z, W, Yt);
  k_gemm<<<256, 512, 0, stream>>>(Ab, Yt, Pb);
  k_reduce<<<2048, 256, 0, stream>>>(Pb, out);
}